// Round 17
// baseline (1790.086 us; speedup 1.0000x reference)
//
#include <hip/hip_runtime.h>

// QuantumMicroTransformer forward, MI355X (gfx950).
// Round 17: R16 (1746.7us) + (a) non-temporal C stores in the final GEMM (write-once output
// stops evicting reused B panels from L2/L3), (b) wtrans blocks cover 4 k-tiles each (grid
// 50048 -> 12512 blocks for Wout; 8192 -> 2048 for the 8 proj mats). All else byte-identical.

#define DEVINL __device__ __forceinline__

typedef float f32x4 __attribute__((ext_vector_type(4)));
typedef __bf16 bf16x8 __attribute__((ext_vector_type(8)));
typedef __bf16 bf16x2v __attribute__((ext_vector_type(2)));

DEVINL unsigned int pk2(float a, float b) {   // packed f32->bf16 RNE, a in low 16
  bf16x2v v;
  v[0] = (__bf16)a;
  v[1] = (__bf16)b;
  return __builtin_bit_cast(unsigned int, v);
}

DEVINL void gload_lds16(const void* g, void* l) {
  __builtin_amdgcn_global_load_lds(
      (const __attribute__((address_space(1))) unsigned int*)g,
      (__attribute__((address_space(3))) unsigned int*)l, 16, 0, 0);
}

// ---------------- PE table: pe[b][h], b in {0,1} (reference indexes pe by BATCH) ---------------
__global__ __launch_bounds__(256) void peinit_kernel(float* __restrict__ pe_tab) {
  const int h = blockIdx.x * 256 + threadIdx.x;   // grid 8 -> h in [0,2048)
  const float c = -9.210340371976184f / 2048.f;   // -ln(10000)/H
  const int i = h >> 1;
  const float dv = expf((float)(2 * i) * c);
#pragma unroll
  for (int b = 0; b < 2; ++b) {
    float ang = (float)b * dv;
    pe_tab[b * 2048 + h] = (h & 1) ? cosf(ang) : sinf(ang);
  }
}

// ---------------- embed + PE (table-driven, vectorized) ----------------------------------------
__global__ __launch_bounds__(256) void embed_kernel(
    const int* __restrict__ src, const float* __restrict__ emb,
    const float* __restrict__ pe_tab, float* __restrict__ x, unsigned short* __restrict__ xbf) {
  const int row = blockIdx.x;                 // b*512 + s
  const int b = row >> 9;
  const int tok = src[row];
  const float sqrtH = 45.25483399593904f;     // sqrt(2048)
  const float* er = emb + (size_t)tok * 2048;
  const float* pr = pe_tab + b * 2048;
  for (int c0 = threadIdx.x * 4; c0 < 2048; c0 += 1024) {
    float4 e = *(const float4*)(er + c0);
    float4 p = *(const float4*)(pr + c0);
    float r0 = fmaf(e.x, sqrtH, p.x), r1 = fmaf(e.y, sqrtH, p.y);
    float r2 = fmaf(e.z, sqrtH, p.z), r3 = fmaf(e.w, sqrtH, p.w);
    *(float4*)(x + (size_t)row * 2048 + c0) = make_float4(r0, r1, r2, r3);
    *(uint2*)&xbf[(size_t)row * 2048 + c0] = make_uint2(pk2(r0, r1), pk2(r2, r3));
  }
}

// ---------------- weight pre-pass: W[2048][N] fp32 -> WT[Npad][2048] bf16 (zero-fill n>=N) ----
DEVINL void wtrans_body(const float* __restrict__ W, unsigned short* __restrict__ WT,
                        const int N, const int n0, const int k0) {
  __shared__ float t[64][65];
  const int tid = threadIdx.x;
  const int c4 = (tid & 15) * 4;
#pragma unroll
  for (int it = 0; it < 4; ++it) {
    int kl = it * 16 + (tid >> 4);
    int n = n0 + c4;
    float4 wv;
    if (n + 3 < N) {
      wv = *(const float4*)(W + (size_t)(k0 + kl) * N + n);
    } else {
      wv.x = (n + 0 < N) ? W[(size_t)(k0 + kl) * N + n + 0] : 0.f;
      wv.y = (n + 1 < N) ? W[(size_t)(k0 + kl) * N + n + 1] : 0.f;
      wv.z = (n + 2 < N) ? W[(size_t)(k0 + kl) * N + n + 2] : 0.f;
      wv.w = (n + 3 < N) ? W[(size_t)(k0 + kl) * N + n + 3] : 0.f;
    }
    t[kl][c4 + 0] = wv.x;
    t[kl][c4 + 1] = wv.y;
    t[kl][c4 + 2] = wv.z;
    t[kl][c4 + 3] = wv.w;
  }
  __syncthreads();
  const int kp = (tid & 7) * 8;
#pragma unroll
  for (int j = 0; j < 2; ++j) {
    int nl = j * 32 + (tid >> 3);
    uint4 u;
    u.x = pk2(t[kp + 0][nl], t[kp + 1][nl]);
    u.y = pk2(t[kp + 2][nl], t[kp + 3][nl]);
    u.z = pk2(t[kp + 4][nl], t[kp + 5][nl]);
    u.w = pk2(t[kp + 6][nl], t[kp + 7][nl]);
    *(uint4*)&WT[(size_t)(n0 + nl) * 2048 + k0 + kp] = u;
  }
}

// each block handles 4 consecutive 64-k tiles (grid.y = 2048/256 = 8)
__global__ __launch_bounds__(256) void wtrans_kernel(
    const float* __restrict__ W, unsigned short* __restrict__ WT, const int N) {
#pragma unroll
  for (int it = 0; it < 4; ++it) {
    if (it) __syncthreads();
    wtrans_body(W, WT, N, blockIdx.x * 64, blockIdx.y * 256 + it * 64);
  }
}

// all 8 projection weights in one dispatch: z = l*4 + {q,k,v,o}
__global__ __launch_bounds__(256) void wtrans8_kernel(
    const float* __restrict__ Wq, const float* __restrict__ Wk,
    const float* __restrict__ Wv, const float* __restrict__ Wo,
    unsigned short* __restrict__ WTp) {
  const int z = blockIdx.z, l = z >> 2, mt = z & 3;
  const float* Wm = (mt == 0) ? Wq : (mt == 1) ? Wk : (mt == 2) ? Wv : Wo;
#pragma unroll
  for (int it = 0; it < 4; ++it) {
    if (it) __syncthreads();
    wtrans_body(Wm + (size_t)l * 2048 * 2048,
                WTp + (size_t)z * 2048 * 2048, 2048,
                blockIdx.x * 64, blockIdx.y * 256 + it * 64);
  }
}

// ================= bf16-B GEMM, 256-thread body (measured; QKV & O-proj) =======================
// C[M,NN] = A[M,2048] @ BT^T + bias. 4 waves 2x2; tile BM x BN; BK=32; double-buffered.
template <int BM, int BN, int NN>
DEVINL void gemm_bf_body(const unsigned short* __restrict__ A,
                         const unsigned short* __restrict__ BT,
                         const float* __restrict__ bias, float* __restrict__ C,
                         const int m0, const int n0) {
  constexpr int K = 2048;
  constexpr int WM = BM / 32;
  constexpr int NF = BN / 32;                 // B-frags per wave
  __shared__ __align__(16) unsigned short A_lds[2][BM * 32];
  __shared__ __align__(16) unsigned short B_lds[2][BN * 32];

  const int tid = threadIdx.x;
  const int w = tid >> 6, lane = tid & 63;
  const int wm = w >> 1, wn = w & 1;

  const int aRow = lane >> 2;
  const int aChunk = (lane & 3) ^ ((lane >> 3) & 3);

  int aOff[WM], bOff[NF];
#pragma unroll
  for (int mi = 0; mi < WM; ++mi) {
    int m = wm * (BM / 2) + mi * 16 + (lane & 15);
    aOff[mi] = m * 32 + ((lane >> 4) ^ ((m >> 1) & 3)) * 8;
  }
#pragma unroll
  for (int ni = 0; ni < NF; ++ni) {
    int n = wn * (BN / 2) + ni * 16 + (lane & 15);
    bOff[ni] = n * 32 + ((lane >> 4) ^ ((n >> 1) & 3)) * 8;
  }

  f32x4 acc[WM][NF] = {};

  auto stage = [&](int k0, int bf) {
#pragma unroll
    for (int i = 0; i < BM / 64; ++i) {       // A: BM rows
      int r0 = (w * (BM / 64) + i) * 16;
      gload_lds16(A + (size_t)(m0 + r0 + aRow) * K + k0 + aChunk * 8, &A_lds[bf][r0 * 32]);
    }
#pragma unroll
    for (int i = 0; i < BN / 64; ++i) {       // B: BN rows
      int r0 = (w * (BN / 64) + i) * 16;
      gload_lds16(BT + (size_t)(n0 + r0 + aRow) * K + k0 + aChunk * 8, &B_lds[bf][r0 * 32]);
    }
  };
  auto compute = [&](int bf) {
    bf16x8 af[WM], bfr[NF];
#pragma unroll
    for (int mi = 0; mi < WM; ++mi) af[mi] = *(const bf16x8*)&A_lds[bf][aOff[mi]];
#pragma unroll
    for (int ni = 0; ni < NF; ++ni) bfr[ni] = *(const bf16x8*)&B_lds[bf][bOff[ni]];
#pragma unroll
    for (int mi = 0; mi < WM; ++mi)
#pragma unroll
      for (int ni = 0; ni < NF; ++ni)
        acc[mi][ni] = __builtin_amdgcn_mfma_f32_16x16x32_bf16(af[mi], bfr[ni], acc[mi][ni], 0, 0, 0);
  };

  stage(0, 0);
  __syncthreads();
  int buf = 0;
  for (int t = 0; t < K / 32 - 1; ++t) {
    stage((t + 1) * 32, buf ^ 1);   // async global->LDS into other buffer
    compute(buf);                   // MFMA hides the in-flight loads
    __syncthreads();                // drains vmcnt -> other buffer ready
    buf ^= 1;
  }
  compute(buf);

  const int r0w = (lane >> 4) * 4;            // C/D: col = lane&15, row = (lane>>4)*4 + reg
  const int lrow = lane & 15;
#pragma unroll
  for (int mi = 0; mi < WM; ++mi)
#pragma unroll
    for (int ni = 0; ni < NF; ++ni) {
      int ccol = n0 + wn * (BN / 2) + ni * 16 + lrow;
      if ((NN % BN == 0) || ccol < NN) {
        float bv = bias[ccol];
#pragma unroll
        for (int r = 0; r < 4; ++r) {
          int crow = m0 + wm * (BM / 2) + mi * 16 + r0w + r;
          C[(size_t)crow * NN + ccol] = acc[mi][ni][r] + bv;
        }
      }
    }
}

template <int BM, int BN, int NN>
__global__ __launch_bounds__(256) void gemm_bf_kernel(
    const unsigned short* __restrict__ A, const unsigned short* __restrict__ BT,
    const float* __restrict__ bias, float* __restrict__ C) {
  gemm_bf_body<BM, BN, NN>(A, BT, bias, C, blockIdx.x * BM, blockIdx.y * BN);
}

__global__ __launch_bounds__(256) void gemm_qkv_bf_kernel(
    const unsigned short* __restrict__ A, const unsigned short* __restrict__ WT,  // 3 mats packed
    const float* __restrict__ bq, const float* __restrict__ bk, const float* __restrict__ bv,
    float* __restrict__ q, float* __restrict__ k, float* __restrict__ v) {
  const int z = blockIdx.z;
  const unsigned short* BT = WT + (size_t)z * 2048 * 2048;
  const float* bias = (z == 0) ? bq : (z == 1) ? bk : bv;
  float* C = (z == 0) ? q : (z == 1) ? k : v;
  gemm_bf_body<64, 128, 2048>(A, BT, bias, C, blockIdx.x * 64, blockIdx.y * 128);
}

// ================= final GEMM: 128x256 tile, 512 threads / 8 waves (2x4), per-wave 64x64 =======
// 16 MFMA per barrier per wave. LDS 48KB; grid 8 x 391 = 3128 (bijective XCD swizzle).
// Non-temporal C stores: the 400MB write-once output doesn't evict reused B panels.
__global__ __launch_bounds__(512) void gemm_final_bf_kernel(
    const unsigned short* __restrict__ A, const unsigned short* __restrict__ BT,
    const float* __restrict__ bias, float* __restrict__ C) {
  constexpr int K = 2048;
  constexpr int NN = 100000;
  const int bid = blockIdx.x;
  const int f = (bid & 7) * (gridDim.x >> 3) + (bid >> 3);
  const int m0 = (f & 7) * 128, n0 = (f >> 3) * 256;

  __shared__ __align__(16) unsigned short A_lds[2][128 * 32];
  __shared__ __align__(16) unsigned short B_lds[2][256 * 32];

  const int tid = threadIdx.x;
  const int w = tid >> 6, lane = tid & 63;    // 8 waves
  const int wm = w >> 2, wn = w & 3;          // 2 x 4

  const int aRow = lane >> 2;
  const int aChunk = (lane & 3) ^ ((lane >> 3) & 3);

  int aOff[4], bOff[4];
#pragma unroll
  for (int mi = 0; mi < 4; ++mi) {
    int m = wm * 64 + mi * 16 + (lane & 15);
    aOff[mi] = m * 32 + ((lane >> 4) ^ ((m >> 1) & 3)) * 8;
  }
#pragma unroll
  for (int ni = 0; ni < 4; ++ni) {
    int n = wn * 64 + ni * 16 + (lane & 15);
    bOff[ni] = n * 32 + ((lane >> 4) ^ ((n >> 1) & 3)) * 8;
  }

  f32x4 acc[4][4] = {};

  auto stage = [&](int k0, int bf) {
    int r0 = w * 16;                          // A: wave w covers rows [w*16, w*16+16)
    gload_lds16(A + (size_t)(m0 + r0 + aRow) * K + k0 + aChunk * 8, &A_lds[bf][r0 * 32]);
#pragma unroll
    for (int i = 0; i < 2; ++i) {             // B: wave w covers rows [w*32, w*32+32)
      int rb = (w * 2 + i) * 16;
      gload_lds16(BT + (size_t)(n0 + rb + aRow) * K + k0 + aChunk * 8, &B_lds[bf][rb * 32]);
    }
  };
  auto compute = [&](int bf) {
    bf16x8 af[4], bfr[4];
#pragma unroll
    for (int mi = 0; mi < 4; ++mi) af[mi] = *(const bf16x8*)&A_lds[bf][aOff[mi]];
#pragma unroll
    for (int ni = 0; ni < 4; ++ni) bfr[ni] = *(const bf16x8*)&B_lds[bf][bOff[ni]];
#pragma unroll
    for (int mi = 0; mi < 4; ++mi)
#pragma unroll
      for (int ni = 0; ni < 4; ++ni)
        acc[mi][ni] = __builtin_amdgcn_mfma_f32_16x16x32_bf16(af[mi], bfr[ni], acc[mi][ni], 0, 0, 0);
  };

  stage(0, 0);
  __syncthreads();
  int buf = 0;
  for (int t = 0; t < K / 32 - 1; ++t) {
    stage((t + 1) * 32, buf ^ 1);
    compute(buf);
    __syncthreads();
    buf ^= 1;
  }
  compute(buf);

  const int r0w = (lane >> 4) * 4;            // C/D: col = lane&15, row = (lane>>4)*4 + reg
  const int lrow = lane & 15;
#pragma unroll
  for (int mi = 0; mi < 4; ++mi)
#pragma unroll
    for (int ni = 0; ni < 4; ++ni) {
      int ccol = n0 + wn * 64 + ni * 16 + lrow;
      if (ccol < NN) {
        float bv = bias[ccol];
#pragma unroll
        for (int r = 0; r < 4; ++r) {
          int crow = m0 + wm * 64 + mi * 16 + r0w + r;
          __builtin_nontemporal_store(acc[mi][ni][r] + bv, &C[(size_t)crow * NN + ccol]);
        }
      }
    }
}

// ================= fp32-B GEMM (fallback path, measured Round-4 config) ========================
template <int BM>
DEVINL void gemm_body(const unsigned short* __restrict__ A, const float* __restrict__ B,
                      const float* __restrict__ bias, float* __restrict__ C,
                      const int N, const int m0, const int n0) {
  constexpr int K = 2048;
  constexpr int WM = BM / 32;
  constexpr int AI = BM / 64;
  __shared__ __align__(16) unsigned short A_lds[2][BM * 32];
  __shared__ __align__(16) unsigned short B_lds[2][128 * 32];

  const int tid = threadIdx.x;
  const int w = tid >> 6, lane = tid & 63;
  const int wm = w >> 1, wn = w & 1;

  const int n_local = tid & 127;
  const int kq = tid >> 7;
  const int col = n0 + n_local;
  const bool colok = col < N;
  const int bswz = (n_local >> 1) & 3;

  const int aRow = lane >> 2;
  const int aChunk = (lane & 3) ^ ((lane >> 3) & 3);

  int aOff[WM], bOff[4];
#pragma unroll
  for (int mi = 0; mi < WM; ++mi) {
    int m = wm * (BM / 2) + mi * 16 + (lane & 15);
    aOff[mi] = m * 32 + ((lane >> 4) ^ ((m >> 1) & 3)) * 8;
  }
#pragma unroll
  for (int ni = 0; ni < 4; ++ni) {
    int n = wn * 64 + ni * 16 + (lane & 15);
    bOff[ni] = n * 32 + ((lane >> 4) ^ ((n >> 1) & 3)) * 8;
  }

  f32x4 acc[WM][4] = {};
  float fB[16];

  auto stageA = [&](int k0, int bf) {
#pragma unroll
    for (int i = 0; i < AI; ++i) {
      int r0 = (w * AI + i) * 16;
      gload_lds16(A + (size_t)(m0 + r0 + aRow) * K + k0 + aChunk * 8, &A_lds[bf][r0 * 32]);
    }
  };
  auto loadB = [&](int k0) {
#pragma unroll
    for (int g = 0; g < 4; ++g) {
      int kl = (g * 2 + kq) * 4;
#pragma unroll
      for (int i = 0; i < 4; ++i)
        fB[g * 4 + i] = colok ? B[(size_t)(k0 + kl + i) * N + col] : 0.f;
    }
  };
  auto writeB = [&](int bf) {
#pragma unroll
    for (int g = 0; g < 4; ++g) {
      int kl = (g * 2 + kq) * 4;
      uint2 p = make_uint2(pk2(fB[g * 4 + 0], fB[g * 4 + 1]),
                           pk2(fB[g * 4 + 2], fB[g * 4 + 3]));
      int chunk = (kl >> 3) ^ bswz;
      *(uint2*)&B_lds[bf][n_local * 32 + chunk * 8 + (kl & 7)] = p;
    }
  };
  auto compute = [&](int bf) {
    bf16x8 af[WM], bfr[4];
#pragma unroll
    for (int mi = 0; mi < WM; ++mi) af[mi] = *(const bf16x8*)&A_lds[bf][aOff[mi]];
#pragma unroll
    for (int ni = 0; ni < 4; ++ni) bfr[ni] = *(const bf16x8*)&B_lds[bf][bOff[ni]];
#pragma unroll
    for (int mi = 0; mi < WM; ++mi)
#pragma unroll
      for (int ni = 0; ni < 4; ++ni)
        acc[mi][ni] = __builtin_amdgcn_mfma_f32_16x16x32_bf16(af[mi], bfr[ni], acc[mi][ni], 0, 0, 0);
  };

  stageA(0, 0);
  loadB(0);
  writeB(0);
  __syncthreads();
  int buf = 0;
  for (int t = 0; t < K / 32 - 1; ++t) {
    stageA((t + 1) * 32, buf ^ 1);
    loadB((t + 1) * 32);
    compute(buf);
    writeB(buf ^ 1);
    __syncthreads();
    buf ^= 1;
  }
  compute(buf);

  const int r0w = (lane >> 4) * 4;
  const int lrow = lane & 15;
#pragma unroll
  for (int mi = 0; mi < WM; ++mi)
#pragma unroll
    for (int ni = 0; ni < 4; ++ni) {
      int ccol = n0 + wn * 64 + ni * 16 + lrow;
      if (ccol < N) {
        float bv = bias[ccol];
#pragma unroll
        for (int r = 0; r < 4; ++r) {
          int crow = m0 + wm * (BM / 2) + mi * 16 + r0w + r;
          C[(size_t)crow * N + ccol] = acc[mi][ni][r] + bv;
        }
      }
    }
}

__global__ __launch_bounds__(256) void gemm_qkv_kernel(
    const unsigned short* __restrict__ A,
    const float* __restrict__ Wq, const float* __restrict__ Wk, const float* __restrict__ Wv,
    const float* __restrict__ bq, const float* __restrict__ bk, const float* __restrict__ bv,
    float* __restrict__ q, float* __restrict__ k, float* __restrict__ v) {
  const int z = blockIdx.z;
  const float* B = (z == 0) ? Wq : (z == 1) ? Wk : Wv;
  const float* bias = (z == 0) ? bq : (z == 1) ? bk : bv;
  float* C = (z == 0) ? q : (z == 1) ? k : v;
  gemm_body<64>(A, B, bias, C, 2048, blockIdx.x * 64, blockIdx.y * 128);
}

template <int BM>
__global__ __launch_bounds__(256) void gemm_kernel(
    const unsigned short* __restrict__ A, const float* __restrict__ B,
    const float* __restrict__ bias, float* __restrict__ C, const int N) {
  gemm_body<BM>(A, B, bias, C, N, blockIdx.x * BM, blockIdx.y * 128);
}

__global__ __launch_bounds__(256) void gemm_final_kernel(
    const unsigned short* __restrict__ A, const float* __restrict__ B,
    const float* __restrict__ bias, float* __restrict__ C, const int N) {
  const int bid = blockIdx.x;
  const int f = (bid & 7) * (gridDim.x >> 3) + (bid >> 3);
  gemm_body<128>(A, B, bias, C, N, (f & 7) * 128, (f >> 3) * 128);
}

// ---------------- fused attention, pair-split (R9/R12 measured): 2 threads per query row ------
__global__ __launch_bounds__(256) void attn_kernel(
    const float* __restrict__ q, const float* __restrict__ k,
    const float* __restrict__ v, unsigned short* __restrict__ o) {
  __shared__ __align__(16) float K_lds[512 * 32];   // 64KB -> 2 blocks/CU
  const int tid = threadIdx.x;
  const int blk = blockIdx.x;                 // 0..511
  const int bh = blk >> 2, chunk = blk & 3;
  const int b = bh >> 6, h = bh & 63;
  const size_t headoff = (size_t)b * 512 * 2048 + (size_t)h * 32;

  const float* kb = k + headoff;
#pragma unroll
  for (int i = 0; i < 16; ++i) {
    int flat = i * 256 + tid;                 // float4 id (4096 total)
    int j = flat >> 3, d4 = flat & 7;
    *(float4*)&K_lds[j * 32 + d4 * 4] = *(const float4*)(kb + (size_t)j * 2048 + d4 * 4);
  }
  __syncthreads();

  const int row = chunk * 128 + (tid >> 1);   // s in [0,512)
  const int half = tid & 1;
  const int j0 = half * 256, j1 = j0 + 256;
  const float* qr = q + headoff + (size_t)row * 2048;
  float4 Q[8];
#pragma unroll
  for (int d = 0; d < 8; ++d) Q[d] = *(const float4*)(qr + d * 4);

  const float scale = 0.17677669529663689f;   // 1/sqrt(32)
  auto dot = [&](int j) -> float {
    const float4* kr = (const float4*)&K_lds[j * 32];
    float p0 = 0.f, p1 = 0.f, p2 = 0.f, p3 = 0.f;
#pragma unroll
    for (int d = 0; d < 8; ++d) {
      float4 kk = kr[d];
      p0 = fmaf(Q[d].x, kk.x, p0);
      p1 = fmaf(Q[d].y, kk.y, p1);
      p2 = fmaf(Q[d].z, kk.z, p2);
      p3 = fmaf(Q[d].w, kk.w, p3);
    }
    return ((p0 + p1) + (p2 + p3)) * scale;
  };

  // pass 1: online max + softmax denominator over own half, then pair-combine
  float m = -1e30f, denom = 0.f;
  for (int j = j0; j < j1; ++j) {
    float s = dot(j);
    float nm = fmaxf(m, s);
    denom = denom * __expf(m - nm) + __expf(s - nm);
    m = nm;
  }
  {
    float m2 = __shfl_xor(m, 1);
    float d2 = __shfl_xor(denom, 1);
    float mm = fmaxf(m, m2);
    denom = denom * __expf(m - mm) + d2 * __expf(m2 - mm);
    m = mm;
  }
  const float invd = 1.f / denom;

  // pass 2: sum of exp(softmax) over own half, pair-combine
  float sum_e = 0.f;
  for (int j = j0; j < j1; ++j) {
    float a = __expf(dot(j) - m) * invd;
    sum_e += __expf(a);
  }
  sum_e += __shfl_xor(sum_e, 1);
  const float inv_se = 1.f / (sum_e + 1e-6f);

  // pass 3: cw = a2*sigmoid(a2), accumulate cw @ V over own half (V row software-prefetched)
  float4 accv[8];
#pragma unroll
  for (int d = 0; d < 8; ++d) accv[d] = make_float4(0.f, 0.f, 0.f, 0.f);
  const float* vb = v + headoff;
  float4 vcur[8];
#pragma unroll
  for (int d = 0; d < 8; ++d) vcur[d] = *(const float4*)(vb + (size_t)j0 * 2048 + d * 4);
  for (int j = j0; j < j1; ++j) {
    float4 vnxt[8];
    if (j + 1 < j1) {
      const float4* vr = (const float4*)(vb + (size_t)(j + 1) * 2048);
#pragma unroll
      for (int d = 0; d < 8; ++d) vnxt[d] = vr[d];
    } else {
#pragma unroll
      for (int d = 0; d < 8; ++d) vnxt[d] = vcur[d];
    }
    float a = __expf(dot(j) - m) * invd;
    float e = __expf(a);
    float a2 = e * inv_se;
    float cw = a2 / (1.f + __expf(-a2));
#pragma unroll
    for (int d = 0; d < 8; ++d) {
      accv[d].x = fmaf(cw, vcur[d].x, accv[d].x);
      accv[d].y = fmaf(cw, vcur[d].y, accv[d].y);
      accv[d].z = fmaf(cw, vcur[d].z, accv[d].z);
      accv[d].w = fmaf(cw, vcur[d].w, accv[d].w);
    }
#pragma unroll
    for (int d = 0; d < 8; ++d) vcur[d] = vnxt[d];
  }
  // pair-combine the 32-float accumulator; each thread writes its 4 float4-groups
#pragma unroll
  for (int d = 0; d < 8; ++d) {
    accv[d].x += __shfl_xor(accv[d].x, 1);
    accv[d].y += __shfl_xor(accv[d].y, 1);
    accv[d].z += __shfl_xor(accv[d].z, 1);
    accv[d].w += __shfl_xor(accv[d].w, 1);
  }
  unsigned short* orow = o + headoff + (size_t)row * 2048;
#pragma unroll
  for (int g = 0; g < 4; ++g) {
    int d = half * 4 + g;
    uint2 p = make_uint2(pk2(accv[d].x, accv[d].y), pk2(accv[d].z, accv[d].w));
    *(uint2*)&orow[d * 4] = p;
  }
}

// ---------------- residual + sr_norm with quake fast_inv_sqrt (bit-faithful) -------------------
__global__ __launch_bounds__(256) void norm_kernel(
    const float* __restrict__ o, const float* __restrict__ xin,
    const float* __restrict__ w, const float* __restrict__ bb,
    float* __restrict__ xout, unsigned short* __restrict__ xbf) {
  __shared__ float red[4];
  const int row = blockIdx.x, tid = threadIdx.x;
  const float* op = o + (size_t)row * 2048;
  const float* xp = xin + (size_t)row * 2048;
  float4 hv[2];
#pragma unroll
  for (int i = 0; i < 2; ++i) {
    float4 a = *(const float4*)(op + tid * 4 + i * 1024);
    float4 c = *(const float4*)(xp + tid * 4 + i * 1024);
    hv[i] = make_float4(a.x + c.x, a.y + c.y, a.z + c.z, a.w + c.w);
  }
  float s = 0.f;
#pragma unroll
  for (int i = 0; i < 2; ++i) s += hv[i].x + hv[i].y + hv[i].z + hv[i].w;
  for (int off = 32; off; off >>= 1) s += __shfl_down(s, off);
  if ((tid & 63) == 0) red[tid >> 6] = s;
  __syncthreads();
  const float mean = (red[0] + red[1] + red[2] + red[3]) * (1.f / 2048.f);
  __syncthreads();

  float vs = 0.f;
#pragma unroll
  for (int i = 0; i < 2; ++i) {
    float dx = hv[i].x - mean, dy = hv[i].y - mean, dz = hv[i].z - mean, dw = hv[i].w - mean;
    vs += dx * dx + dy * dy + dz * dz + dw * dw;
  }
  for (int off = 32; off; off >>= 1) vs += __shfl_down(vs, off);
  if ((tid & 63) == 0) red[tid >> 6] = vs;
  __syncthreads();
  const float var = (red[0] + red[1] + red[2] + red[3]) * (1.f / 2048.f);

  // quake fast inverse sqrt, exactly as reference
  const float xv = var + 1e-5f;
  int ii = __float_as_int(xv);
  ii = 1597463007 - (ii >> 1);
  float y = __int_as_float(ii);
  y = y * (1.5f - 0.5f * xv * y * y);

#pragma unroll
  for (int i = 0; i < 2; ++i) {
    int c0 = tid * 4 + i * 1024;
    float4 wv = *(const float4*)(w + c0);
    float4 bv = *(const float4*)(bb + c0);
    float r0 = wv.x * ((hv[i].x - mean) * y) + bv.x;
    float r1 = wv.y * ((hv[i].y - mean) * y) + bv.y;
    float r2 = wv.z * ((hv[i].z - mean) * y) + bv.z;
    float r3 = wv.w * ((hv[i].w - mean) * y) + bv.w;
    *(float4*)(xout + (size_t)row * 2048 + c0) = make_float4(r0, r1, r2, r3);
    *(uint2*)&xbf[(size_t)row * 2048 + c0] = make_uint2(pk2(r0, r1), pk2(r2, r3));
  }
}

// ---------------- launch -----------------------------------------------------------------------
extern "C" void kernel_launch(void* const* d_in, const int* in_sizes, int n_in,
                              void* d_out, int out_size, void* d_ws, size_t ws_size,
                              hipStream_t stream) {
  const int*   src  = (const int*)d_in[0];
  const float* emb  = (const float*)d_in[1];
  const float* Wq   = (const float*)d_in[2];
  const float* bq   = (const float*)d_in[3];
  const float* Wk   = (const float*)d_in[4];
  const float* bk   = (const float*)d_in[5];
  const float* Wv   = (const float*)d_in[6];
  const float* bv   = (const float*)d_in[7];
  const float* Wo   = (const float*)d_in[8];
  const float* bo   = (const float*)d_in[9];
  const float* nw   = (const float*)d_in[10];
  const float* nb   = (const float*)d_in[11];
  const float* Wout = (const float*)d_in[12];
  const float* bout = (const float*)d_in[13];
  float* out = (float*)d_out;

  char* ws = (char*)d_ws;
  float* x  = (float*)(ws);
  float* qb = (float*)(ws + (8ll << 20));
  float* kb = (float*)(ws + (16ll << 20));
  float* vb = (float*)(ws + (24ll << 20));
  float* ob = (float*)(ws + (32ll << 20));
  unsigned short* xbf = (unsigned short*)(ws + (40ll << 20));
  unsigned short* abf = (unsigned short*)(ws + (44ll << 20));
  float* pe_tab = ob;                         // 16KB, consumed by embed before ob is written

  // big-ws layout: 8 proj WT at 48MB (8 x 8MB), Wout^T (padded to 100096 rows) at 112MB
  const unsigned long long NEED = (112ull << 20) + 100096ull * 2048ull * 2ull;  // 527,433,728
  const bool big = (unsigned long long)ws_size >= NEED;
  unsigned short* WTp = (unsigned short*)(ws + (48ll << 20));
  unsigned short* WTo = (unsigned short*)(ws + (112ll << 20));

  peinit_kernel<<<8, 256, 0, stream>>>(pe_tab);
  embed_kernel<<<1024, 256, 0, stream>>>(src, emb, pe_tab, x, xbf);

  if (big) {
    // one-time weight transpose+cvt pre-pass (8 proj mats in one dispatch, then Wout)
    wtrans8_kernel<<<dim3(32, 8, 8), 256, 0, stream>>>(Wq, Wk, Wv, Wo, WTp);
    wtrans_kernel<<<dim3(1564, 8), 256, 0, stream>>>(Wout, WTo, 100000);  // 1564*64 = 100096

    for (int l = 0; l < 2; ++l) {
      const size_t bo_ = (size_t)l * 2048;
      const unsigned short* WTl = WTp + (size_t)(l * 4) * 2048 * 2048;
      gemm_qkv_bf_kernel<<<dim3(16, 16, 3), 256, 0, stream>>>(
          xbf, WTl, bq + bo_, bk + bo_, bv + bo_, qb, kb, vb);
      attn_kernel<<<512, 256, 0, stream>>>(qb, kb, vb, abf);
      gemm_bf_kernel<64, 64, 2048><<<dim3(16, 32), 256, 0, stream>>>(
          abf, WTl + (size_t)3 * 2048 * 2048, bo + bo_, ob);
      norm_kernel<<<1024, 256, 0, stream>>>(ob, x, nw + bo_, nb + bo_, x, xbf);
    }
    // final: 8 M-blocks x 391 N-blocks of 256 = 3128 (divisible by 8 -> bijective XCD swizzle)
    gemm_final_bf_kernel<<<8 * 391, 512, 0, stream>>>(xbf, WTo, bout, out);
  } else {
    // fallback: measured Round-4 path (fp32-B in-loop staging)
    for (int l = 0; l < 2; ++l) {
      const size_t wo_ = (size_t)l * 2048 * 2048;
      const size_t bo_ = (size_t)l * 2048;
      gemm_qkv_kernel<<<dim3(16, 16, 3), 256, 0, stream>>>(
          xbf, Wq + wo_, Wk + wo_, Wv + wo_, bq + bo_, bk + bo_, bv + bo_, qb, kb, vb);
      attn_kernel<<<512, 256, 0, stream>>>(qb, kb, vb, abf);
      gemm_kernel<64><<<dim3(16, 16), 256, 0, stream>>>(abf, Wo + wo_, bo + bo_, ob, 2048);
      norm_kernel<<<1024, 256, 0, stream>>>(ob, x, nw + bo_, nb + bo_, x, xbf);
    }
    gemm_final_kernel<<<8 * 782, 256, 0, stream>>>(xbf, Wout, bout, out, 100000);
  }
}

// Round 18
// 1745.225 us; speedup vs baseline: 1.0257x; 1.0257x over previous
//
#include <hip/hip_runtime.h>

// QuantumMicroTransformer forward, MI355X (gfx950).
// Round 18: R16 restored byte-exact (measured best 1746.7us). R17's non-temporal C stores
// caused 1.37x write amplification (WRITE 403->551MB: NT bypasses L2 write-combining of the
// scalar fp32 epilogue stores) and are reverted, along with the inseparable wtrans coarsening.

#define DEVINL __device__ __forceinline__

typedef float f32x4 __attribute__((ext_vector_type(4)));
typedef __bf16 bf16x8 __attribute__((ext_vector_type(8)));
typedef __bf16 bf16x2v __attribute__((ext_vector_type(2)));

DEVINL unsigned int pk2(float a, float b) {   // packed f32->bf16 RNE, a in low 16
  bf16x2v v;
  v[0] = (__bf16)a;
  v[1] = (__bf16)b;
  return __builtin_bit_cast(unsigned int, v);
}

DEVINL void gload_lds16(const void* g, void* l) {
  __builtin_amdgcn_global_load_lds(
      (const __attribute__((address_space(1))) unsigned int*)g,
      (__attribute__((address_space(3))) unsigned int*)l, 16, 0, 0);
}

// ---------------- PE table: pe[b][h], b in {0,1} (reference indexes pe by BATCH) ---------------
__global__ __launch_bounds__(256) void peinit_kernel(float* __restrict__ pe_tab) {
  const int h = blockIdx.x * 256 + threadIdx.x;   // grid 8 -> h in [0,2048)
  const float c = -9.210340371976184f / 2048.f;   // -ln(10000)/H
  const int i = h >> 1;
  const float dv = expf((float)(2 * i) * c);
#pragma unroll
  for (int b = 0; b < 2; ++b) {
    float ang = (float)b * dv;
    pe_tab[b * 2048 + h] = (h & 1) ? cosf(ang) : sinf(ang);
  }
}

// ---------------- embed + PE (table-driven, vectorized) ----------------------------------------
__global__ __launch_bounds__(256) void embed_kernel(
    const int* __restrict__ src, const float* __restrict__ emb,
    const float* __restrict__ pe_tab, float* __restrict__ x, unsigned short* __restrict__ xbf) {
  const int row = blockIdx.x;                 // b*512 + s
  const int b = row >> 9;
  const int tok = src[row];
  const float sqrtH = 45.25483399593904f;     // sqrt(2048)
  const float* er = emb + (size_t)tok * 2048;
  const float* pr = pe_tab + b * 2048;
  for (int c0 = threadIdx.x * 4; c0 < 2048; c0 += 1024) {
    float4 e = *(const float4*)(er + c0);
    float4 p = *(const float4*)(pr + c0);
    float r0 = fmaf(e.x, sqrtH, p.x), r1 = fmaf(e.y, sqrtH, p.y);
    float r2 = fmaf(e.z, sqrtH, p.z), r3 = fmaf(e.w, sqrtH, p.w);
    *(float4*)(x + (size_t)row * 2048 + c0) = make_float4(r0, r1, r2, r3);
    *(uint2*)&xbf[(size_t)row * 2048 + c0] = make_uint2(pk2(r0, r1), pk2(r2, r3));
  }
}

// ---------------- weight pre-pass: W[2048][N] fp32 -> WT[Npad][2048] bf16 (zero-fill n>=N) ----
DEVINL void wtrans_body(const float* __restrict__ W, unsigned short* __restrict__ WT,
                        const int N, const int n0, const int k0) {
  __shared__ float t[64][65];
  const int tid = threadIdx.x;
  const int c4 = (tid & 15) * 4;
#pragma unroll
  for (int it = 0; it < 4; ++it) {
    int kl = it * 16 + (tid >> 4);
    int n = n0 + c4;
    float4 wv;
    if (n + 3 < N) {
      wv = *(const float4*)(W + (size_t)(k0 + kl) * N + n);
    } else {
      wv.x = (n + 0 < N) ? W[(size_t)(k0 + kl) * N + n + 0] : 0.f;
      wv.y = (n + 1 < N) ? W[(size_t)(k0 + kl) * N + n + 1] : 0.f;
      wv.z = (n + 2 < N) ? W[(size_t)(k0 + kl) * N + n + 2] : 0.f;
      wv.w = (n + 3 < N) ? W[(size_t)(k0 + kl) * N + n + 3] : 0.f;
    }
    t[kl][c4 + 0] = wv.x;
    t[kl][c4 + 1] = wv.y;
    t[kl][c4 + 2] = wv.z;
    t[kl][c4 + 3] = wv.w;
  }
  __syncthreads();
  const int kp = (tid & 7) * 8;
#pragma unroll
  for (int j = 0; j < 2; ++j) {
    int nl = j * 32 + (tid >> 3);
    uint4 u;
    u.x = pk2(t[kp + 0][nl], t[kp + 1][nl]);
    u.y = pk2(t[kp + 2][nl], t[kp + 3][nl]);
    u.z = pk2(t[kp + 4][nl], t[kp + 5][nl]);
    u.w = pk2(t[kp + 6][nl], t[kp + 7][nl]);
    *(uint4*)&WT[(size_t)(n0 + nl) * 2048 + k0 + kp] = u;
  }
}

__global__ __launch_bounds__(256) void wtrans_kernel(
    const float* __restrict__ W, unsigned short* __restrict__ WT, const int N) {
  wtrans_body(W, WT, N, blockIdx.x * 64, blockIdx.y * 64);
}

// all 8 projection weights in one dispatch: z = l*4 + {q,k,v,o}
__global__ __launch_bounds__(256) void wtrans8_kernel(
    const float* __restrict__ Wq, const float* __restrict__ Wk,
    const float* __restrict__ Wv, const float* __restrict__ Wo,
    unsigned short* __restrict__ WTp) {
  const int z = blockIdx.z, l = z >> 2, mt = z & 3;
  const float* Wm = (mt == 0) ? Wq : (mt == 1) ? Wk : (mt == 2) ? Wv : Wo;
  wtrans_body(Wm + (size_t)l * 2048 * 2048,
              WTp + (size_t)z * 2048 * 2048, 2048, blockIdx.x * 64, blockIdx.y * 64);
}

// ================= bf16-B GEMM, 256-thread body (measured; QKV & O-proj) =======================
// C[M,NN] = A[M,2048] @ BT^T + bias. 4 waves 2x2; tile BM x BN; BK=32; double-buffered.
template <int BM, int BN, int NN>
DEVINL void gemm_bf_body(const unsigned short* __restrict__ A,
                         const unsigned short* __restrict__ BT,
                         const float* __restrict__ bias, float* __restrict__ C,
                         const int m0, const int n0) {
  constexpr int K = 2048;
  constexpr int WM = BM / 32;
  constexpr int NF = BN / 32;                 // B-frags per wave
  __shared__ __align__(16) unsigned short A_lds[2][BM * 32];
  __shared__ __align__(16) unsigned short B_lds[2][BN * 32];

  const int tid = threadIdx.x;
  const int w = tid >> 6, lane = tid & 63;
  const int wm = w >> 1, wn = w & 1;

  const int aRow = lane >> 2;
  const int aChunk = (lane & 3) ^ ((lane >> 3) & 3);

  int aOff[WM], bOff[NF];
#pragma unroll
  for (int mi = 0; mi < WM; ++mi) {
    int m = wm * (BM / 2) + mi * 16 + (lane & 15);
    aOff[mi] = m * 32 + ((lane >> 4) ^ ((m >> 1) & 3)) * 8;
  }
#pragma unroll
  for (int ni = 0; ni < NF; ++ni) {
    int n = wn * (BN / 2) + ni * 16 + (lane & 15);
    bOff[ni] = n * 32 + ((lane >> 4) ^ ((n >> 1) & 3)) * 8;
  }

  f32x4 acc[WM][NF] = {};

  auto stage = [&](int k0, int bf) {
#pragma unroll
    for (int i = 0; i < BM / 64; ++i) {       // A: BM rows
      int r0 = (w * (BM / 64) + i) * 16;
      gload_lds16(A + (size_t)(m0 + r0 + aRow) * K + k0 + aChunk * 8, &A_lds[bf][r0 * 32]);
    }
#pragma unroll
    for (int i = 0; i < BN / 64; ++i) {       // B: BN rows
      int r0 = (w * (BN / 64) + i) * 16;
      gload_lds16(BT + (size_t)(n0 + r0 + aRow) * K + k0 + aChunk * 8, &B_lds[bf][r0 * 32]);
    }
  };
  auto compute = [&](int bf) {
    bf16x8 af[WM], bfr[NF];
#pragma unroll
    for (int mi = 0; mi < WM; ++mi) af[mi] = *(const bf16x8*)&A_lds[bf][aOff[mi]];
#pragma unroll
    for (int ni = 0; ni < NF; ++ni) bfr[ni] = *(const bf16x8*)&B_lds[bf][bOff[ni]];
#pragma unroll
    for (int mi = 0; mi < WM; ++mi)
#pragma unroll
      for (int ni = 0; ni < NF; ++ni)
        acc[mi][ni] = __builtin_amdgcn_mfma_f32_16x16x32_bf16(af[mi], bfr[ni], acc[mi][ni], 0, 0, 0);
  };

  stage(0, 0);
  __syncthreads();
  int buf = 0;
  for (int t = 0; t < K / 32 - 1; ++t) {
    stage((t + 1) * 32, buf ^ 1);   // async global->LDS into other buffer
    compute(buf);                   // MFMA hides the in-flight loads
    __syncthreads();                // drains vmcnt -> other buffer ready
    buf ^= 1;
  }
  compute(buf);

  const int r0w = (lane >> 4) * 4;            // C/D: col = lane&15, row = (lane>>4)*4 + reg
  const int lrow = lane & 15;
#pragma unroll
  for (int mi = 0; mi < WM; ++mi)
#pragma unroll
    for (int ni = 0; ni < NF; ++ni) {
      int ccol = n0 + wn * (BN / 2) + ni * 16 + lrow;
      if ((NN % BN == 0) || ccol < NN) {
        float bv = bias[ccol];
#pragma unroll
        for (int r = 0; r < 4; ++r) {
          int crow = m0 + wm * (BM / 2) + mi * 16 + r0w + r;
          C[(size_t)crow * NN + ccol] = acc[mi][ni][r] + bv;
        }
      }
    }
}

template <int BM, int BN, int NN>
__global__ __launch_bounds__(256) void gemm_bf_kernel(
    const unsigned short* __restrict__ A, const unsigned short* __restrict__ BT,
    const float* __restrict__ bias, float* __restrict__ C) {
  gemm_bf_body<BM, BN, NN>(A, BT, bias, C, blockIdx.x * BM, blockIdx.y * BN);
}

__global__ __launch_bounds__(256) void gemm_qkv_bf_kernel(
    const unsigned short* __restrict__ A, const unsigned short* __restrict__ WT,  // 3 mats packed
    const float* __restrict__ bq, const float* __restrict__ bk, const float* __restrict__ bv,
    float* __restrict__ q, float* __restrict__ k, float* __restrict__ v) {
  const int z = blockIdx.z;
  const unsigned short* BT = WT + (size_t)z * 2048 * 2048;
  const float* bias = (z == 0) ? bq : (z == 1) ? bk : bv;
  float* C = (z == 0) ? q : (z == 1) ? k : v;
  gemm_bf_body<64, 128, 2048>(A, BT, bias, C, blockIdx.x * 64, blockIdx.y * 128);
}

// ================= final GEMM: 128x256 tile, 512 threads / 8 waves (2x4), per-wave 64x64 =======
// 16 MFMA per barrier per wave. LDS 48KB; grid 8 x 391 = 3128 (bijective XCD swizzle).
// B (WTo) padded to 100096 rows so staging of the last panel is in-bounds; C-write guarded.
__global__ __launch_bounds__(512) void gemm_final_bf_kernel(
    const unsigned short* __restrict__ A, const unsigned short* __restrict__ BT,
    const float* __restrict__ bias, float* __restrict__ C) {
  constexpr int K = 2048;
  constexpr int NN = 100000;
  const int bid = blockIdx.x;
  const int f = (bid & 7) * (gridDim.x >> 3) + (bid >> 3);
  const int m0 = (f & 7) * 128, n0 = (f >> 3) * 256;

  __shared__ __align__(16) unsigned short A_lds[2][128 * 32];
  __shared__ __align__(16) unsigned short B_lds[2][256 * 32];

  const int tid = threadIdx.x;
  const int w = tid >> 6, lane = tid & 63;    // 8 waves
  const int wm = w >> 2, wn = w & 3;          // 2 x 4

  const int aRow = lane >> 2;
  const int aChunk = (lane & 3) ^ ((lane >> 3) & 3);

  int aOff[4], bOff[4];
#pragma unroll
  for (int mi = 0; mi < 4; ++mi) {
    int m = wm * 64 + mi * 16 + (lane & 15);
    aOff[mi] = m * 32 + ((lane >> 4) ^ ((m >> 1) & 3)) * 8;
  }
#pragma unroll
  for (int ni = 0; ni < 4; ++ni) {
    int n = wn * 64 + ni * 16 + (lane & 15);
    bOff[ni] = n * 32 + ((lane >> 4) ^ ((n >> 1) & 3)) * 8;
  }

  f32x4 acc[4][4] = {};

  auto stage = [&](int k0, int bf) {
    int r0 = w * 16;                          // A: wave w covers rows [w*16, w*16+16)
    gload_lds16(A + (size_t)(m0 + r0 + aRow) * K + k0 + aChunk * 8, &A_lds[bf][r0 * 32]);
#pragma unroll
    for (int i = 0; i < 2; ++i) {             // B: wave w covers rows [w*32, w*32+32)
      int rb = (w * 2 + i) * 16;
      gload_lds16(BT + (size_t)(n0 + rb + aRow) * K + k0 + aChunk * 8, &B_lds[bf][rb * 32]);
    }
  };
  auto compute = [&](int bf) {
    bf16x8 af[4], bfr[4];
#pragma unroll
    for (int mi = 0; mi < 4; ++mi) af[mi] = *(const bf16x8*)&A_lds[bf][aOff[mi]];
#pragma unroll
    for (int ni = 0; ni < 4; ++ni) bfr[ni] = *(const bf16x8*)&B_lds[bf][bOff[ni]];
#pragma unroll
    for (int mi = 0; mi < 4; ++mi)
#pragma unroll
      for (int ni = 0; ni < 4; ++ni)
        acc[mi][ni] = __builtin_amdgcn_mfma_f32_16x16x32_bf16(af[mi], bfr[ni], acc[mi][ni], 0, 0, 0);
  };

  stage(0, 0);
  __syncthreads();
  int buf = 0;
  for (int t = 0; t < K / 32 - 1; ++t) {
    stage((t + 1) * 32, buf ^ 1);
    compute(buf);
    __syncthreads();
    buf ^= 1;
  }
  compute(buf);

  const int r0w = (lane >> 4) * 4;            // C/D: col = lane&15, row = (lane>>4)*4 + reg
  const int lrow = lane & 15;
#pragma unroll
  for (int mi = 0; mi < 4; ++mi)
#pragma unroll
    for (int ni = 0; ni < 4; ++ni) {
      int ccol = n0 + wn * 64 + ni * 16 + lrow;
      if (ccol < NN) {
        float bv = bias[ccol];
#pragma unroll
        for (int r = 0; r < 4; ++r) {
          int crow = m0 + wm * 64 + mi * 16 + r0w + r;
          C[(size_t)crow * NN + ccol] = acc[mi][ni][r] + bv;
        }
      }
    }
}

// ================= fp32-B GEMM (fallback path, measured Round-4 config) ========================
template <int BM>
DEVINL void gemm_body(const unsigned short* __restrict__ A, const float* __restrict__ B,
                      const float* __restrict__ bias, float* __restrict__ C,
                      const int N, const int m0, const int n0) {
  constexpr int K = 2048;
  constexpr int WM = BM / 32;
  constexpr int AI = BM / 64;
  __shared__ __align__(16) unsigned short A_lds[2][BM * 32];
  __shared__ __align__(16) unsigned short B_lds[2][128 * 32];

  const int tid = threadIdx.x;
  const int w = tid >> 6, lane = tid & 63;
  const int wm = w >> 1, wn = w & 1;

  const int n_local = tid & 127;
  const int kq = tid >> 7;
  const int col = n0 + n_local;
  const bool colok = col < N;
  const int bswz = (n_local >> 1) & 3;

  const int aRow = lane >> 2;
  const int aChunk = (lane & 3) ^ ((lane >> 3) & 3);

  int aOff[WM], bOff[4];
#pragma unroll
  for (int mi = 0; mi < WM; ++mi) {
    int m = wm * (BM / 2) + mi * 16 + (lane & 15);
    aOff[mi] = m * 32 + ((lane >> 4) ^ ((m >> 1) & 3)) * 8;
  }
#pragma unroll
  for (int ni = 0; ni < 4; ++ni) {
    int n = wn * 64 + ni * 16 + (lane & 15);
    bOff[ni] = n * 32 + ((lane >> 4) ^ ((n >> 1) & 3)) * 8;
  }

  f32x4 acc[WM][4] = {};
  float fB[16];

  auto stageA = [&](int k0, int bf) {
#pragma unroll
    for (int i = 0; i < AI; ++i) {
      int r0 = (w * AI + i) * 16;
      gload_lds16(A + (size_t)(m0 + r0 + aRow) * K + k0 + aChunk * 8, &A_lds[bf][r0 * 32]);
    }
  };
  auto loadB = [&](int k0) {
#pragma unroll
    for (int g = 0; g < 4; ++g) {
      int kl = (g * 2 + kq) * 4;
#pragma unroll
      for (int i = 0; i < 4; ++i)
        fB[g * 4 + i] = colok ? B[(size_t)(k0 + kl + i) * N + col] : 0.f;
    }
  };
  auto writeB = [&](int bf) {
#pragma unroll
    for (int g = 0; g < 4; ++g) {
      int kl = (g * 2 + kq) * 4;
      uint2 p = make_uint2(pk2(fB[g * 4 + 0], fB[g * 4 + 1]),
                           pk2(fB[g * 4 + 2], fB[g * 4 + 3]));
      int chunk = (kl >> 3) ^ bswz;
      *(uint2*)&B_lds[bf][n_local * 32 + chunk * 8 + (kl & 7)] = p;
    }
  };
  auto compute = [&](int bf) {
    bf16x8 af[WM], bfr[4];
#pragma unroll
    for (int mi = 0; mi < WM; ++mi) af[mi] = *(const bf16x8*)&A_lds[bf][aOff[mi]];
#pragma unroll
    for (int ni = 0; ni < 4; ++ni) bfr[ni] = *(const bf16x8*)&B_lds[bf][bOff[ni]];
#pragma unroll
    for (int mi = 0; mi < WM; ++mi)
#pragma unroll
      for (int ni = 0; ni < 4; ++ni)
        acc[mi][ni] = __builtin_amdgcn_mfma_f32_16x16x32_bf16(af[mi], bfr[ni], acc[mi][ni], 0, 0, 0);
  };

  stageA(0, 0);
  loadB(0);
  writeB(0);
  __syncthreads();
  int buf = 0;
  for (int t = 0; t < K / 32 - 1; ++t) {
    stageA((t + 1) * 32, buf ^ 1);
    loadB((t + 1) * 32);
    compute(buf);
    writeB(buf ^ 1);
    __syncthreads();
    buf ^= 1;
  }
  compute(buf);

  const int r0w = (lane >> 4) * 4;
  const int lrow = lane & 15;
#pragma unroll
  for (int mi = 0; mi < WM; ++mi)
#pragma unroll
    for (int ni = 0; ni < 4; ++ni) {
      int ccol = n0 + wn * 64 + ni * 16 + lrow;
      if (ccol < N) {
        float bv = bias[ccol];
#pragma unroll
        for (int r = 0; r < 4; ++r) {
          int crow = m0 + wm * (BM / 2) + mi * 16 + r0w + r;
          C[(size_t)crow * N + ccol] = acc[mi][ni][r] + bv;
        }
      }
    }
}

__global__ __launch_bounds__(256) void gemm_qkv_kernel(
    const unsigned short* __restrict__ A,
    const float* __restrict__ Wq, const float* __restrict__ Wk, const float* __restrict__ Wv,
    const float* __restrict__ bq, const float* __restrict__ bk, const float* __restrict__ bv,
    float* __restrict__ q, float* __restrict__ k, float* __restrict__ v) {
  const int z = blockIdx.z;
  const float* B = (z == 0) ? Wq : (z == 1) ? Wk : Wv;
  const float* bias = (z == 0) ? bq : (z == 1) ? bk : bv;
  float* C = (z == 0) ? q : (z == 1) ? k : v;
  gemm_body<64>(A, B, bias, C, 2048, blockIdx.x * 64, blockIdx.y * 128);
}

template <int BM>
__global__ __launch_bounds__(256) void gemm_kernel(
    const unsigned short* __restrict__ A, const float* __restrict__ B,
    const float* __restrict__ bias, float* __restrict__ C, const int N) {
  gemm_body<BM>(A, B, bias, C, N, blockIdx.x * BM, blockIdx.y * 128);
}

__global__ __launch_bounds__(256) void gemm_final_kernel(
    const unsigned short* __restrict__ A, const float* __restrict__ B,
    const float* __restrict__ bias, float* __restrict__ C, const int N) {
  const int bid = blockIdx.x;
  const int f = (bid & 7) * (gridDim.x >> 3) + (bid >> 3);
  gemm_body<128>(A, B, bias, C, N, (f & 7) * 128, (f >> 3) * 128);
}

// ---------------- fused attention, pair-split (R9/R12 measured): 2 threads per query row ------
__global__ __launch_bounds__(256) void attn_kernel(
    const float* __restrict__ q, const float* __restrict__ k,
    const float* __restrict__ v, unsigned short* __restrict__ o) {
  __shared__ __align__(16) float K_lds[512 * 32];   // 64KB -> 2 blocks/CU
  const int tid = threadIdx.x;
  const int blk = blockIdx.x;                 // 0..511
  const int bh = blk >> 2, chunk = blk & 3;
  const int b = bh >> 6, h = bh & 63;
  const size_t headoff = (size_t)b * 512 * 2048 + (size_t)h * 32;

  const float* kb = k + headoff;
#pragma unroll
  for (int i = 0; i < 16; ++i) {
    int flat = i * 256 + tid;                 // float4 id (4096 total)
    int j = flat >> 3, d4 = flat & 7;
    *(float4*)&K_lds[j * 32 + d4 * 4] = *(const float4*)(kb + (size_t)j * 2048 + d4 * 4);
  }
  __syncthreads();

  const int row = chunk * 128 + (tid >> 1);   // s in [0,512)
  const int half = tid & 1;
  const int j0 = half * 256, j1 = j0 + 256;
  const float* qr = q + headoff + (size_t)row * 2048;
  float4 Q[8];
#pragma unroll
  for (int d = 0; d < 8; ++d) Q[d] = *(const float4*)(qr + d * 4);

  const float scale = 0.17677669529663689f;   // 1/sqrt(32)
  auto dot = [&](int j) -> float {
    const float4* kr = (const float4*)&K_lds[j * 32];
    float p0 = 0.f, p1 = 0.f, p2 = 0.f, p3 = 0.f;
#pragma unroll
    for (int d = 0; d < 8; ++d) {
      float4 kk = kr[d];
      p0 = fmaf(Q[d].x, kk.x, p0);
      p1 = fmaf(Q[d].y, kk.y, p1);
      p2 = fmaf(Q[d].z, kk.z, p2);
      p3 = fmaf(Q[d].w, kk.w, p3);
    }
    return ((p0 + p1) + (p2 + p3)) * scale;
  };

  // pass 1: online max + softmax denominator over own half, then pair-combine
  float m = -1e30f, denom = 0.f;
  for (int j = j0; j < j1; ++j) {
    float s = dot(j);
    float nm = fmaxf(m, s);
    denom = denom * __expf(m - nm) + __expf(s - nm);
    m = nm;
  }
  {
    float m2 = __shfl_xor(m, 1);
    float d2 = __shfl_xor(denom, 1);
    float mm = fmaxf(m, m2);
    denom = denom * __expf(m - mm) + d2 * __expf(m2 - mm);
    m = mm;
  }
  const float invd = 1.f / denom;

  // pass 2: sum of exp(softmax) over own half, pair-combine
  float sum_e = 0.f;
  for (int j = j0; j < j1; ++j) {
    float a = __expf(dot(j) - m) * invd;
    sum_e += __expf(a);
  }
  sum_e += __shfl_xor(sum_e, 1);
  const float inv_se = 1.f / (sum_e + 1e-6f);

  // pass 3: cw = a2*sigmoid(a2), accumulate cw @ V over own half (V row software-prefetched)
  float4 accv[8];
#pragma unroll
  for (int d = 0; d < 8; ++d) accv[d] = make_float4(0.f, 0.f, 0.f, 0.f);
  const float* vb = v + headoff;
  float4 vcur[8];
#pragma unroll
  for (int d = 0; d < 8; ++d) vcur[d] = *(const float4*)(vb + (size_t)j0 * 2048 + d * 4);
  for (int j = j0; j < j1; ++j) {
    float4 vnxt[8];
    if (j + 1 < j1) {
      const float4* vr = (const float4*)(vb + (size_t)(j + 1) * 2048);
#pragma unroll
      for (int d = 0; d < 8; ++d) vnxt[d] = vr[d];
    } else {
#pragma unroll
      for (int d = 0; d < 8; ++d) vnxt[d] = vcur[d];
    }
    float a = __expf(dot(j) - m) * invd;
    float e = __expf(a);
    float a2 = e * inv_se;
    float cw = a2 / (1.f + __expf(-a2));
#pragma unroll
    for (int d = 0; d < 8; ++d) {
      accv[d].x = fmaf(cw, vcur[d].x, accv[d].x);
      accv[d].y = fmaf(cw, vcur[d].y, accv[d].y);
      accv[d].z = fmaf(cw, vcur[d].z, accv[d].z);
      accv[d].w = fmaf(cw, vcur[d].w, accv[d].w);
    }
#pragma unroll
    for (int d = 0; d < 8; ++d) vcur[d] = vnxt[d];
  }
  // pair-combine the 32-float accumulator; each thread writes its 4 float4-groups
#pragma unroll
  for (int d = 0; d < 8; ++d) {
    accv[d].x += __shfl_xor(accv[d].x, 1);
    accv[d].y += __shfl_xor(accv[d].y, 1);
    accv[d].z += __shfl_xor(accv[d].z, 1);
    accv[d].w += __shfl_xor(accv[d].w, 1);
  }
  unsigned short* orow = o + headoff + (size_t)row * 2048;
#pragma unroll
  for (int g = 0; g < 4; ++g) {
    int d = half * 4 + g;
    uint2 p = make_uint2(pk2(accv[d].x, accv[d].y), pk2(accv[d].z, accv[d].w));
    *(uint2*)&orow[d * 4] = p;
  }
}

// ---------------- residual + sr_norm with quake fast_inv_sqrt (bit-faithful) -------------------
__global__ __launch_bounds__(256) void norm_kernel(
    const float* __restrict__ o, const float* __restrict__ xin,
    const float* __restrict__ w, const float* __restrict__ bb,
    float* __restrict__ xout, unsigned short* __restrict__ xbf) {
  __shared__ float red[4];
  const int row = blockIdx.x, tid = threadIdx.x;
  const float* op = o + (size_t)row * 2048;
  const float* xp = xin + (size_t)row * 2048;
  float4 hv[2];
#pragma unroll
  for (int i = 0; i < 2; ++i) {
    float4 a = *(const float4*)(op + tid * 4 + i * 1024);
    float4 c = *(const float4*)(xp + tid * 4 + i * 1024);
    hv[i] = make_float4(a.x + c.x, a.y + c.y, a.z + c.z, a.w + c.w);
  }
  float s = 0.f;
#pragma unroll
  for (int i = 0; i < 2; ++i) s += hv[i].x + hv[i].y + hv[i].z + hv[i].w;
  for (int off = 32; off; off >>= 1) s += __shfl_down(s, off);
  if ((tid & 63) == 0) red[tid >> 6] = s;
  __syncthreads();
  const float mean = (red[0] + red[1] + red[2] + red[3]) * (1.f / 2048.f);
  __syncthreads();

  float vs = 0.f;
#pragma unroll
  for (int i = 0; i < 2; ++i) {
    float dx = hv[i].x - mean, dy = hv[i].y - mean, dz = hv[i].z - mean, dw = hv[i].w - mean;
    vs += dx * dx + dy * dy + dz * dz + dw * dw;
  }
  for (int off = 32; off; off >>= 1) vs += __shfl_down(vs, off);
  if ((tid & 63) == 0) red[tid >> 6] = vs;
  __syncthreads();
  const float var = (red[0] + red[1] + red[2] + red[3]) * (1.f / 2048.f);

  // quake fast inverse sqrt, exactly as reference
  const float xv = var + 1e-5f;
  int ii = __float_as_int(xv);
  ii = 1597463007 - (ii >> 1);
  float y = __int_as_float(ii);
  y = y * (1.5f - 0.5f * xv * y * y);

#pragma unroll
  for (int i = 0; i < 2; ++i) {
    int c0 = tid * 4 + i * 1024;
    float4 wv = *(const float4*)(w + c0);
    float4 bv = *(const float4*)(bb + c0);
    float r0 = wv.x * ((hv[i].x - mean) * y) + bv.x;
    float r1 = wv.y * ((hv[i].y - mean) * y) + bv.y;
    float r2 = wv.z * ((hv[i].z - mean) * y) + bv.z;
    float r3 = wv.w * ((hv[i].w - mean) * y) + bv.w;
    *(float4*)(xout + (size_t)row * 2048 + c0) = make_float4(r0, r1, r2, r3);
    *(uint2*)&xbf[(size_t)row * 2048 + c0] = make_uint2(pk2(r0, r1), pk2(r2, r3));
  }
}

// ---------------- launch -----------------------------------------------------------------------
extern "C" void kernel_launch(void* const* d_in, const int* in_sizes, int n_in,
                              void* d_out, int out_size, void* d_ws, size_t ws_size,
                              hipStream_t stream) {
  const int*   src  = (const int*)d_in[0];
  const float* emb  = (const float*)d_in[1];
  const float* Wq   = (const float*)d_in[2];
  const float* bq   = (const float*)d_in[3];
  const float* Wk   = (const float*)d_in[4];
  const float* bk   = (const float*)d_in[5];
  const float* Wv   = (const float*)d_in[6];
  const float* bv   = (const float*)d_in[7];
  const float* Wo   = (const float*)d_in[8];
  const float* bo   = (const float*)d_in[9];
  const float* nw   = (const float*)d_in[10];
  const float* nb   = (const float*)d_in[11];
  const float* Wout = (const float*)d_in[12];
  const float* bout = (const float*)d_in[13];
  float* out = (float*)d_out;

  char* ws = (char*)d_ws;
  float* x  = (float*)(ws);
  float* qb = (float*)(ws + (8ll << 20));
  float* kb = (float*)(ws + (16ll << 20));
  float* vb = (float*)(ws + (24ll << 20));
  float* ob = (float*)(ws + (32ll << 20));
  unsigned short* xbf = (unsigned short*)(ws + (40ll << 20));
  unsigned short* abf = (unsigned short*)(ws + (44ll << 20));
  float* pe_tab = ob;                         // 16KB, consumed by embed before ob is written

  // big-ws layout: 8 proj WT at 48MB (8 x 8MB), Wout^T (padded to 100096 rows) at 112MB
  const unsigned long long NEED = (112ull << 20) + 100096ull * 2048ull * 2ull;  // 527,433,728
  const bool big = (unsigned long long)ws_size >= NEED;
  unsigned short* WTp = (unsigned short*)(ws + (48ll << 20));
  unsigned short* WTo = (unsigned short*)(ws + (112ll << 20));

  peinit_kernel<<<8, 256, 0, stream>>>(pe_tab);
  embed_kernel<<<1024, 256, 0, stream>>>(src, emb, pe_tab, x, xbf);

  if (big) {
    // one-time weight transpose+cvt pre-pass (8 proj mats in one dispatch, then Wout)
    wtrans8_kernel<<<dim3(32, 32, 8), 256, 0, stream>>>(Wq, Wk, Wv, Wo, WTp);
    wtrans_kernel<<<dim3(1564, 32), 256, 0, stream>>>(Wout, WTo, 100000);  // 1564*64 = 100096

    for (int l = 0; l < 2; ++l) {
      const size_t bo_ = (size_t)l * 2048;
      const unsigned short* WTl = WTp + (size_t)(l * 4) * 2048 * 2048;
      gemm_qkv_bf_kernel<<<dim3(16, 16, 3), 256, 0, stream>>>(
          xbf, WTl, bq + bo_, bk + bo_, bv + bo_, qb, kb, vb);
      attn_kernel<<<512, 256, 0, stream>>>(qb, kb, vb, abf);
      gemm_bf_kernel<64, 64, 2048><<<dim3(16, 32), 256, 0, stream>>>(
          abf, WTl + (size_t)3 * 2048 * 2048, bo + bo_, ob);
      norm_kernel<<<1024, 256, 0, stream>>>(ob, x, nw + bo_, nb + bo_, x, xbf);
    }
    // final: 8 M-blocks x 391 N-blocks of 256 = 3128 (divisible by 8 -> bijective XCD swizzle)
    gemm_final_bf_kernel<<<8 * 391, 512, 0, stream>>>(xbf, WTo, bout, out);
  } else {
    // fallback: measured Round-4 path (fp32-B in-loop staging)
    for (int l = 0; l < 2; ++l) {
      const size_t wo_ = (size_t)l * 2048 * 2048;
      const size_t bo_ = (size_t)l * 2048;
      gemm_qkv_kernel<<<dim3(16, 16, 3), 256, 0, stream>>>(
          xbf, Wq + wo_, Wk + wo_, Wv + wo_, bq + bo_, bk + bo_, bv + bo_, qb, kb, vb);
      attn_kernel<<<512, 256, 0, stream>>>(qb, kb, vb, abf);
      gemm_kernel<64><<<dim3(16, 16), 256, 0, stream>>>(abf, Wo + wo_, bo + bo_, ob, 2048);
      norm_kernel<<<1024, 256, 0, stream>>>(ob, x, nw + bo_, nb + bo_, x, xbf);
    }
    gemm_final_kernel<<<8 * 782, 256, 0, stream>>>(xbf, Wout, bout, out, 100000);
  }
}